// Round 10
// baseline (170.331 us; speedup 1.0000x reference)
//
#include <hip/hip_runtime.h>
#include <hip/hip_bf16.h>

typedef __attribute__((ext_vector_type(8))) short short8;
typedef __attribute__((ext_vector_type(4))) float f32x4;

#define MFMA16(a,b,c) __builtin_amdgcn_mfma_f32_16x16x32_bf16((a),(b),(c),0,0,0)

static __device__ __forceinline__ unsigned int f2bf(float f){
    unsigned int u = __float_as_uint(f);
    u += 0x7FFFu + ((u >> 16) & 1u);
    return u >> 16;
}

static __device__ __forceinline__ short8 pack8(float4 a, float4 b){
    short8 r;
    r[0]=(short)f2bf(a.x); r[1]=(short)f2bf(a.y);
    r[2]=(short)f2bf(a.z); r[3]=(short)f2bf(a.w);
    r[4]=(short)f2bf(b.x); r[5]=(short)f2bf(b.y);
    r[6]=(short)f2bf(b.z); r[7]=(short)f2bf(b.w);
    return r;
}

// ---- mask -> bit-packed [b][q][32 words]; dtype sniff merged (per-block:
// int32 bools are all in {0,1}; byte-bools set bytes 1..3 in any 2048 words).
__global__ __launch_bounds__(256) void mask_prep_k(
    const unsigned int* __restrict__ m, unsigned int* __restrict__ bmout)
{
    __shared__ int any_hi;
    const int tid  = threadIdx.x;
    const int lane = tid & 63;
    const unsigned int gbase = blockIdx.x*256u + tid;
    if (tid == 0) any_hi = 0;

    unsigned int wv[8]; unsigned int acc = 0;
    #pragma unroll
    for (int it = 0; it < 8; ++it){
        wv[it] = m[it*262144u + gbase];
        acc |= wv[it];
    }
    __syncthreads();
    if (acc & 0xFFFFFF00u) atomicOr(&any_hi, 1);
    __syncthreads();

    if (any_hi == 0){
        // int32 layout: 8.4M words, ballot 64 -> one u64 per wave-iter
        for (int it = 0; it < 32; ++it){
            unsigned int idx = it*262144u + gbase;
            unsigned int v = m[idx];
            unsigned long long bal = __ballot(v != 0u);
            if (lane == 0)
                *(unsigned long long*)(bmout + (idx >> 5)) = bal;
        }
    } else {
        // byte layout: 2.1M u32 words (4 bools each) — already loaded
        #pragma unroll
        for (int it = 0; it < 8; ++it){
            unsigned int idx = it*262144u + gbase;
            unsigned int v = wv[it];
            unsigned int nib = (v | (v>>7) | (v>>14) | (v>>21)) & 0xFu;
            unsigned int x = nib << ((lane & 7)*4);
            x |= (unsigned int)__shfl_xor((int)x, 1);
            x |= (unsigned int)__shfl_xor((int)x, 2);
            x |= (unsigned int)__shfl_xor((int)x, 4);
            if ((lane & 7) == 0)
                bmout[idx >> 3] = x;
        }
    }
}

// ---------------- QKV projection (3-way split grid) ----------------
__global__ __launch_bounds__(256) void qkv_proj_k(
    const float* __restrict__ nd,
    const float* __restrict__ Wqp, const float* __restrict__ bqp,
    const float* __restrict__ Wkp, const float* __restrict__ bkp,
    const float* __restrict__ Wvp, const float* __restrict__ bvp,
    unsigned short* __restrict__ qout, unsigned short* __restrict__ kout,
    unsigned short* __restrict__ vtout)
{
    __shared__ __align__(16) unsigned short xl[64*264];
    const int tid  = threadIdx.x;
    const int bi   = blockIdx.x;          // 384 = 3 kinds x 128 tiles
    const int kind = bi >> 7;
    const int R0   = (bi & 127) * 64;
    const int b    = R0 >> 10;
    const int n0   = R0 & 1023;

    #pragma unroll
    for (int it = 0; it < 16; ++it){
        int f4 = it*256 + tid;
        int r = f4 >> 6, c4 = f4 & 63;
        float4 v = *(const float4*)(nd + (size_t)(R0+r)*256 + c4*4);
        unsigned int lo = f2bf(v.x) | (f2bf(v.y) << 16);
        unsigned int hi = f2bf(v.z) | (f2bf(v.w) << 16);
        *(uint2*)&xl[r*264 + c4*4] = make_uint2(lo, hi);
    }
    __syncthreads();

    const int lane = tid & 63;
    const int w  = tid >> 6;
    const int ln = lane & 15;
    const int g  = lane >> 4;
    const int ow = w * 64;

    f32x4 acc[4][4];
    #pragma unroll
    for (int a=0;a<4;++a){
        #pragma unroll
        for (int c=0;c<4;++c) acc[a][c] = (f32x4){0.f,0.f,0.f,0.f};
    }

    if (kind < 2){
        const float* W  = kind ? Wkp : Wqp;
        const float* bb = kind ? bkp : bqp;
        unsigned short* op = kind ? kout : qout;
        const float scl = kind ? 1.0f : 0.17677669529663687f;
        for (int kk = 0; kk < 8; ++kk){
            short8 wf[4], xf[4];
            #pragma unroll
            for (int ot=0; ot<4; ++ot){
                const float* wp = W + (size_t)(ow + ot*16 + ln)*256 + kk*32 + g*8;
                wf[ot] = pack8(*(const float4*)wp, *(const float4*)(wp+4));
            }
            #pragma unroll
            for (int nt=0; nt<4; ++nt)
                xf[nt] = *(const short8*)&xl[(nt*16+ln)*264 + kk*32 + g*8];
            #pragma unroll
            for (int ot=0; ot<4; ++ot){
                #pragma unroll
                for (int nt=0; nt<4; ++nt)
                    acc[ot][nt] = MFMA16(wf[ot], xf[nt], acc[ot][nt]);
            }
        }
        #pragma unroll
        for (int ot=0; ot<4; ++ot){
            int o0 = ow + ot*16 + g*4;
            int h = o0 >> 5, d0 = o0 & 31;
            float4 b4 = *(const float4*)(bb + o0);
            #pragma unroll
            for (int nt=0; nt<4; ++nt){
                int n = n0 + nt*16 + ln;
                unsigned int lo = f2bf((acc[ot][nt][0]+b4.x)*scl) | (f2bf((acc[ot][nt][1]+b4.y)*scl)<<16);
                unsigned int hi = f2bf((acc[ot][nt][2]+b4.z)*scl) | (f2bf((acc[ot][nt][3]+b4.w)*scl)<<16);
                *(uint2*)(op + ((size_t)(b*8+h)*1024 + n)*32 + d0) = make_uint2(lo,hi);
            }
        }
    } else {
        for (int kk = 0; kk < 8; ++kk){
            short8 wf[4], xf[4];
            #pragma unroll
            for (int ot=0; ot<4; ++ot){
                const float* wp = Wvp + (size_t)(ow + ot*16 + ln)*256 + kk*32 + g*8;
                wf[ot] = pack8(*(const float4*)wp, *(const float4*)(wp+4));
            }
            #pragma unroll
            for (int nt=0; nt<4; ++nt)
                xf[nt] = *(const short8*)&xl[(nt*16+ln)*264 + kk*32 + g*8];
            #pragma unroll
            for (int nt=0; nt<4; ++nt){
                #pragma unroll
                for (int ot=0; ot<4; ++ot)
                    acc[nt][ot] = MFMA16(xf[nt], wf[ot], acc[nt][ot]);
            }
        }
        #pragma unroll
        for (int nt=0; nt<4; ++nt){
            int nb = n0 + nt*16 + g*4;
            #pragma unroll
            for (int ot=0; ot<4; ++ot){
                int o = ow + ot*16 + ln;
                int h = o >> 5, d = o & 31;
                float bvv = bvp[o];
                unsigned int lo = f2bf(acc[nt][ot][0]+bvv) | (f2bf(acc[nt][ot][1]+bvv)<<16);
                unsigned int hi = f2bf(acc[nt][ot][2]+bvv) | (f2bf(acc[nt][ot][3]+bvv)<<16);
                *(uint2*)(vtout + ((size_t)(b*8+h)*32 + d)*1024 + nb) = make_uint2(lo,hi);
            }
        }
    }
}

// ---------------- Fused biased-masked attention ----------------
// Grid 1024 = b(8) x qtile(64) x head-half(2); block 256 thr = 4 waves,
// 1 head/wave -> 4 INDEPENDENT blocks/CU (vs r3's 2): blocks in different
// phases overlap mem/LDS/VALU pipes. Per chunk: kperm zero-shuffle P-frag,
// fixed-max softmax, V+K prefetched one chunk ahead, bias tile 8 KB in LDS
// [4h][16q][32k] with k^(q&7) swizzle (2-way free on writes AND reads).
__global__ __launch_bounds__(256, 4) void attn_k(
    const unsigned short* __restrict__ qbuf, const unsigned short* __restrict__ kbuf,
    const unsigned short* __restrict__ vtbuf, const float* __restrict__ bias,
    const unsigned int* __restrict__ bm, unsigned short* __restrict__ ab)
{
    __shared__ float bs[2048];          // [4 h][16 q][32 k] = 8 KB
    const int tid  = threadIdx.x;
    const int bi   = blockIdx.x;
    const int hh   = bi & 1;            // head half (siblings adjacent -> L2 share)
    const int qt   = (bi >> 1) & 63;
    const int b    = bi >> 7;
    const int q0   = qt * 16;
    const int lane = tid & 63;
    const int w    = tid >> 6;          // wave id = head-local index
    const int ln   = lane & 15;
    const int g    = lane >> 4;
    const int h    = hh*4 + w;

    // Q fragment (B-operand: col=q=ln, k=d=g*8..)
    const short8 qf = *(const short8*)(qbuf + ((size_t)(b*8+h)*1024 + q0 + ln)*32 + g*8);

    // K row permutation: tile row ln -> key 8*(ln>>2)+(ln&3) (+4 for tile 1)
    const int kperm = ((ln >> 2) << 3) + (ln & 3);
    const unsigned short* kp = kbuf  + ((size_t)(b*8+h)*1024 + kperm)*32 + g*8;
    const unsigned short* vp = vtbuf + ((size_t)(b*8+h)*32 + ln)*1024 + g*8;
    const unsigned int* bmp  = bm + (size_t)(b*1024 + q0 + ln)*32;

    // bias staging: thread t covers (q = t>>5 and 8+(t>>5), k = t&31), 4 heads
    const int qt0 = tid >> 5;           // 0..7
    const int kk0 = tid & 31;
    const float* bgp0 = bias + ((size_t)(b*1024 + q0 + qt0)*1024 + kk0)*8 + hh*4;
    const float* bgp1 = bgp0 + 65536;   // +8 q rows
    const int kx  = kk0 ^ qt0;          // swizzle (qt0 = q&7 for both rows)
    const int w0i = qt0*32 + kx;
    const int w1i = w0i + 256;          // (8+qt0)*32 + kx

    // bias read base: [h=w][q=ln][k = 8g + (j ^ (ln&7))]
    const int base_rg = w*512 + ln*32 + g*8;
    const int lnx = ln & 7;

    f32x4 acc0 = (f32x4){0.f,0.f,0.f,0.f};
    f32x4 acc1 = (f32x4){0.f,0.f,0.f,0.f};
    float lsum = 0.f;
    const f32x4 z4 = {0.f,0.f,0.f,0.f};

    float4 br0, br1;
    short8 kA0, kA1, vA0, vA1, kB0, kB1, vB0, vB1;
    unsigned int bmA, bmB;

#define LOAD_BIAS(cc) do { int c_=(cc); \
    br0 = *(const float4*)(bgp0 + c_*256); \
    br1 = *(const float4*)(bgp1 + c_*256); } while(0)

#define STAGE() do { \
    bs[w0i       ] = br0.x; bs[w0i +  512] = br0.y; \
    bs[w0i + 1024] = br0.z; bs[w0i + 1536] = br0.w; \
    bs[w1i       ] = br1.x; bs[w1i +  512] = br1.y; \
    bs[w1i + 1024] = br1.z; bs[w1i + 1536] = br1.w; } while(0)

#define LOAD_KVM(S, cc) do { int c_=(cc); \
    k##S##0 = *(const short8*)(kp + c_*1024); \
    k##S##1 = *(const short8*)(kp + c_*1024 + 128); \
    v##S##0 = *(const short8*)(vp + c_*32); \
    v##S##1 = *(const short8*)(vp + c_*32 + 16*1024); \
    bm##S   = bmp[c_]; } while(0)

#define COMPUTE(S) do { \
    unsigned int mb_ = bm##S >> (g*8); \
    f32x4 s0 = MFMA16(k##S##0, qf, z4); \
    f32x4 s1 = MFMA16(k##S##1, qf, z4); \
    float e0 = __expf(((mb_>>0)&1u) ? -1e30f : s0[0] + bs[base_rg + (0^lnx)]); \
    float e1 = __expf(((mb_>>1)&1u) ? -1e30f : s0[1] + bs[base_rg + (1^lnx)]); \
    float e2 = __expf(((mb_>>2)&1u) ? -1e30f : s0[2] + bs[base_rg + (2^lnx)]); \
    float e3 = __expf(((mb_>>3)&1u) ? -1e30f : s0[3] + bs[base_rg + (3^lnx)]); \
    float e4 = __expf(((mb_>>4)&1u) ? -1e30f : s1[0] + bs[base_rg + (4^lnx)]); \
    float e5 = __expf(((mb_>>5)&1u) ? -1e30f : s1[1] + bs[base_rg + (5^lnx)]); \
    float e6 = __expf(((mb_>>6)&1u) ? -1e30f : s1[2] + bs[base_rg + (6^lnx)]); \
    float e7 = __expf(((mb_>>7)&1u) ? -1e30f : s1[3] + bs[base_rg + (7^lnx)]); \
    lsum += ((e0+e1)+(e2+e3)) + ((e4+e5)+(e6+e7)); \
    int4 pw_ = make_int4( \
        (int)(f2bf(e0) | (f2bf(e1)<<16)), (int)(f2bf(e2) | (f2bf(e3)<<16)), \
        (int)(f2bf(e4) | (f2bf(e5)<<16)), (int)(f2bf(e6) | (f2bf(e7)<<16))); \
    short8 pf_ = *(short8*)&pw_; \
    acc0 = MFMA16(v##S##0, pf_, acc0); \
    acc1 = MFMA16(v##S##1, pf_, acc1); } while(0)

    // prologue: chunk 0 into A-regs + bias regs
    LOAD_BIAS(0);
    LOAD_KVM(A, 0);
    bmA &= ~1u;                         // col 0 force-unmasked (chunk 0 only)

    #pragma unroll 1
    for (int c = 0; c < 32; c += 2){
        // even chunk c: stage bias(c), prefetch bias(c+1)+KVM(c+1), compute(c)
        STAGE();
        LOAD_BIAS(c + 1);
        __syncthreads();
        LOAD_KVM(B, c + 1);
        COMPUTE(A);
        __syncthreads();
        // odd chunk c+1
        STAGE();
        if (c + 2 < 32) LOAD_BIAS(c + 2);
        __syncthreads();
        if (c + 2 < 32) LOAD_KVM(A, c + 2);
        COMPUTE(B);
        __syncthreads();
    }

    float ps = lsum;
    ps += __shfl_xor(ps, 16);
    ps += __shfl_xor(ps, 32);
    float inv = 1.0f / ps;
    {
        size_t orow = ((size_t)(b*1024 + q0 + ln))*256 + h*32;
        unsigned int lo0 = f2bf(acc0[0]*inv) | (f2bf(acc0[1]*inv)<<16);
        unsigned int hi0 = f2bf(acc0[2]*inv) | (f2bf(acc0[3]*inv)<<16);
        *(uint2*)(ab + orow + g*4) = make_uint2(lo0,hi0);
        unsigned int lo1 = f2bf(acc1[0]*inv) | (f2bf(acc1[1]*inv)<<16);
        unsigned int hi1 = f2bf(acc1[2]*inv) | (f2bf(acc1[3]*inv)<<16);
        *(uint2*)(ab + orow + 16 + g*4) = make_uint2(lo1,hi1);
    }
#undef LOAD_BIAS
#undef STAGE
#undef LOAD_KVM
#undef COMPUTE
}

// ---------------- Output projection (32-row tiles) ----------------
__global__ __launch_bounds__(256) void oproj_k(
    const unsigned short* __restrict__ ab, const float* __restrict__ Wop,
    const float* __restrict__ bop, float* __restrict__ out)
{
    __shared__ __align__(16) unsigned short al[32*264];
    const int tid = threadIdx.x;
    const int R0 = blockIdx.x * 32;   // 256 blocks
    #pragma unroll
    for (int it=0; it<4; ++it){
        int f8 = it*256 + tid;
        int r = f8 >> 5, c8 = f8 & 31;
        *(short8*)&al[r*264 + c8*8] = *(const short8*)(ab + (size_t)(R0+r)*256 + c8*8);
    }
    __syncthreads();
    const int lane = tid & 63;
    const int w = tid >> 6, ln = lane & 15, g = lane >> 4;
    const int ow = w*64;
    f32x4 acc[4][2];
    #pragma unroll
    for (int a=0;a<4;++a){ acc[a][0]=(f32x4){0.f,0.f,0.f,0.f}; acc[a][1]=(f32x4){0.f,0.f,0.f,0.f}; }
    for (int kk=0;kk<8;++kk){
        short8 wf[4], xf[2];
        #pragma unroll
        for (int ot=0;ot<4;++ot){
            const float* wp = Wop + (size_t)(ow+ot*16+ln)*256 + kk*32 + g*8;
            wf[ot] = pack8(*(const float4*)wp, *(const float4*)(wp+4));
        }
        #pragma unroll
        for (int nt=0;nt<2;++nt)
            xf[nt] = *(const short8*)&al[(nt*16+ln)*264 + kk*32 + g*8];
        #pragma unroll
        for (int ot=0;ot<4;++ot){
            #pragma unroll
            for (int nt=0;nt<2;++nt)
                acc[ot][nt] = MFMA16(wf[ot], xf[nt], acc[ot][nt]);
        }
    }
    #pragma unroll
    for (int ot=0;ot<4;++ot){
        int o0 = ow + ot*16 + g*4;
        float4 b4 = *(const float4*)(bop + o0);
        #pragma unroll
        for (int nt=0;nt<2;++nt){
            int n = R0 + nt*16 + ln;
            float4 res;
            res.x = acc[ot][nt][0] + b4.x;
            res.y = acc[ot][nt][1] + b4.y;
            res.z = acc[ot][nt][2] + b4.z;
            res.w = acc[ot][nt][3] + b4.w;
            *(float4*)(out + (size_t)n*256 + o0) = res;
        }
    }
}

extern "C" void kernel_launch(void* const* d_in, const int* in_sizes, int n_in,
                              void* d_out, int out_size, void* d_ws, size_t ws_size,
                              hipStream_t stream)
{
    (void)in_sizes; (void)n_in; (void)out_size; (void)ws_size;
    const float* nd   = (const float*)d_in[0];
    // d_in[1] = N scalar (compile-time 1024 here)
    const float* bias = (const float*)d_in[2];
    const int* mask   = (const int*)d_in[3];
    const float* Wq = (const float*)d_in[4];
    const float* bq = (const float*)d_in[5];
    const float* Wk = (const float*)d_in[6];
    const float* bk = (const float*)d_in[7];
    const float* Wv = (const float*)d_in[8];
    const float* bv = (const float*)d_in[9];
    const float* Wo = (const float*)d_in[10];
    const float* bo = (const float*)d_in[11];
    float* out = (float*)d_out;

    const size_t ELEMS = (size_t)8*8*1024*32;   // 2M bf16 per buffer
    unsigned short* qb  = (unsigned short*)d_ws;
    unsigned short* kb  = qb  + ELEMS;
    unsigned short* vtb = kb  + ELEMS;
    unsigned short* ab  = vtb + ELEMS;
    unsigned int* bmw   = (unsigned int*)(ab + ELEMS);  // 1MB bitmask

    mask_prep_k<<<1024, 256, 0, stream>>>((const unsigned int*)mask, bmw);
    qkv_proj_k<<<384, 256, 0, stream>>>(nd, Wq, bq, Wk, bk, Wv, bv, qb, kb, vtb);
    attn_k<<<1024, 256, 0, stream>>>(qb, kb, vtb, bias, bmw, ab);
    oproj_k<<<256, 256, 0, stream>>>(ab, Wo, bo, out);
}

// Round 11
// 143.579 us; speedup vs baseline: 1.1863x; 1.1863x over previous
//
#include <hip/hip_runtime.h>
#include <hip/hip_bf16.h>

typedef __attribute__((ext_vector_type(8))) short short8;
typedef __attribute__((ext_vector_type(4))) float f32x4;

#define MFMA16(a,b,c) __builtin_amdgcn_mfma_f32_16x16x32_bf16((a),(b),(c),0,0,0)

static __device__ __forceinline__ unsigned int f2bf(float f){
    unsigned int u = __float_as_uint(f);
    u += 0x7FFFu + ((u >> 16) & 1u);
    return u >> 16;
}

static __device__ __forceinline__ short8 pack8(float4 a, float4 b){
    short8 r;
    r[0]=(short)f2bf(a.x); r[1]=(short)f2bf(a.y);
    r[2]=(short)f2bf(a.z); r[3]=(short)f2bf(a.w);
    r[4]=(short)f2bf(b.x); r[5]=(short)f2bf(b.y);
    r[6]=(short)f2bf(b.z); r[7]=(short)f2bf(b.w);
    return r;
}

// ---- mask -> bit-packed [b][q][32 words]; dtype sniff merged (per-block:
// int32 bools are all in {0,1}; byte-bools set bytes 1..3 in any 2048 words).
__global__ __launch_bounds__(256) void mask_prep_k(
    const unsigned int* __restrict__ m, unsigned int* __restrict__ bmout)
{
    __shared__ int any_hi;
    const int tid  = threadIdx.x;
    const int lane = tid & 63;
    const unsigned int gbase = blockIdx.x*256u + tid;
    if (tid == 0) any_hi = 0;

    unsigned int wv[8]; unsigned int acc = 0;
    #pragma unroll
    for (int it = 0; it < 8; ++it){
        wv[it] = m[it*262144u + gbase];
        acc |= wv[it];
    }
    __syncthreads();
    if (acc & 0xFFFFFF00u) atomicOr(&any_hi, 1);
    __syncthreads();

    if (any_hi == 0){
        for (int it = 0; it < 32; ++it){
            unsigned int idx = it*262144u + gbase;
            unsigned int v = m[idx];
            unsigned long long bal = __ballot(v != 0u);
            if (lane == 0)
                *(unsigned long long*)(bmout + (idx >> 5)) = bal;
        }
    } else {
        #pragma unroll
        for (int it = 0; it < 8; ++it){
            unsigned int idx = it*262144u + gbase;
            unsigned int v = wv[it];
            unsigned int nib = (v | (v>>7) | (v>>14) | (v>>21)) & 0xFu;
            unsigned int x = nib << ((lane & 7)*4);
            x |= (unsigned int)__shfl_xor((int)x, 1);
            x |= (unsigned int)__shfl_xor((int)x, 2);
            x |= (unsigned int)__shfl_xor((int)x, 4);
            if ((lane & 7) == 0)
                bmout[idx >> 3] = x;
        }
    }
}

// ---------------- QKV projection (3-way split grid) ----------------
__global__ __launch_bounds__(256) void qkv_proj_k(
    const float* __restrict__ nd,
    const float* __restrict__ Wqp, const float* __restrict__ bqp,
    const float* __restrict__ Wkp, const float* __restrict__ bkp,
    const float* __restrict__ Wvp, const float* __restrict__ bvp,
    unsigned short* __restrict__ qout, unsigned short* __restrict__ kout,
    unsigned short* __restrict__ vtout)
{
    __shared__ __align__(16) unsigned short xl[64*264];
    const int tid  = threadIdx.x;
    const int bi   = blockIdx.x;          // 384 = 3 kinds x 128 tiles
    const int kind = bi >> 7;
    const int R0   = (bi & 127) * 64;
    const int b    = R0 >> 10;
    const int n0   = R0 & 1023;

    #pragma unroll
    for (int it = 0; it < 16; ++it){
        int f4 = it*256 + tid;
        int r = f4 >> 6, c4 = f4 & 63;
        float4 v = *(const float4*)(nd + (size_t)(R0+r)*256 + c4*4);
        unsigned int lo = f2bf(v.x) | (f2bf(v.y) << 16);
        unsigned int hi = f2bf(v.z) | (f2bf(v.w) << 16);
        *(uint2*)&xl[r*264 + c4*4] = make_uint2(lo, hi);
    }
    __syncthreads();

    const int lane = tid & 63;
    const int w  = tid >> 6;
    const int ln = lane & 15;
    const int g  = lane >> 4;
    const int ow = w * 64;

    f32x4 acc[4][4];
    #pragma unroll
    for (int a=0;a<4;++a){
        #pragma unroll
        for (int c=0;c<4;++c) acc[a][c] = (f32x4){0.f,0.f,0.f,0.f};
    }

    if (kind < 2){
        const float* W  = kind ? Wkp : Wqp;
        const float* bb = kind ? bkp : bqp;
        unsigned short* op = kind ? kout : qout;
        const float scl = kind ? 1.0f : 0.17677669529663687f;
        for (int kk = 0; kk < 8; ++kk){
            short8 wf[4], xf[4];
            #pragma unroll
            for (int ot=0; ot<4; ++ot){
                const float* wp = W + (size_t)(ow + ot*16 + ln)*256 + kk*32 + g*8;
                wf[ot] = pack8(*(const float4*)wp, *(const float4*)(wp+4));
            }
            #pragma unroll
            for (int nt=0; nt<4; ++nt)
                xf[nt] = *(const short8*)&xl[(nt*16+ln)*264 + kk*32 + g*8];
            #pragma unroll
            for (int ot=0; ot<4; ++ot){
                #pragma unroll
                for (int nt=0; nt<4; ++nt)
                    acc[ot][nt] = MFMA16(wf[ot], xf[nt], acc[ot][nt]);
            }
        }
        #pragma unroll
        for (int ot=0; ot<4; ++ot){
            int o0 = ow + ot*16 + g*4;
            int h = o0 >> 5, d0 = o0 & 31;
            float4 b4 = *(const float4*)(bb + o0);
            #pragma unroll
            for (int nt=0; nt<4; ++nt){
                int n = n0 + nt*16 + ln;
                unsigned int lo = f2bf((acc[ot][nt][0]+b4.x)*scl) | (f2bf((acc[ot][nt][1]+b4.y)*scl)<<16);
                unsigned int hi = f2bf((acc[ot][nt][2]+b4.z)*scl) | (f2bf((acc[ot][nt][3]+b4.w)*scl)<<16);
                *(uint2*)(op + ((size_t)(b*8+h)*1024 + n)*32 + d0) = make_uint2(lo,hi);
            }
        }
    } else {
        for (int kk = 0; kk < 8; ++kk){
            short8 wf[4], xf[4];
            #pragma unroll
            for (int ot=0; ot<4; ++ot){
                const float* wp = Wvp + (size_t)(ow + ot*16 + ln)*256 + kk*32 + g*8;
                wf[ot] = pack8(*(const float4*)wp, *(const float4*)(wp+4));
            }
            #pragma unroll
            for (int nt=0; nt<4; ++nt)
                xf[nt] = *(const short8*)&xl[(nt*16+ln)*264 + kk*32 + g*8];
            #pragma unroll
            for (int nt=0; nt<4; ++nt){
                #pragma unroll
                for (int ot=0; ot<4; ++ot)
                    acc[nt][ot] = MFMA16(xf[nt], wf[ot], acc[nt][ot]);
            }
        }
        #pragma unroll
        for (int nt=0; nt<4; ++nt){
            int nb = n0 + nt*16 + g*4;
            #pragma unroll
            for (int ot=0; ot<4; ++ot){
                int o = ow + ot*16 + ln;
                int h = o >> 5, d = o & 31;
                float bvv = bvp[o];
                unsigned int lo = f2bf(acc[nt][ot][0]+bvv) | (f2bf(acc[nt][ot][1]+bvv)<<16);
                unsigned int hi = f2bf(acc[nt][ot][2]+bvv) | (f2bf(acc[nt][ot][3]+bvv)<<16);
                *(uint2*)(vtout + ((size_t)(b*8+h)*32 + d)*1024 + nb) = make_uint2(lo,hi);
            }
        }
    }
}

// ---------------- Fused biased-masked attention ----------------
// r3's EXACT proven structure (best: 146.9) with 64-key chunks (16 iters):
// same 2-drain-barrier loop, same staging/LDS/bidx/shuffle formulas applied
// verbatim to two 32-key halves (half 1 at LDS +4096, bias regs +256).
// Fixed-max softmax (r8/r10-proven), V lazy from L2 (frees 32 VGPR),
// K snapshot-before-reload (r6 lesson).
__global__ __launch_bounds__(512, 4) void attn_k(
    const unsigned short* __restrict__ qbuf, const unsigned short* __restrict__ kbuf,
    const unsigned short* __restrict__ vtbuf, const float* __restrict__ bias,
    const unsigned int* __restrict__ bm, unsigned short* __restrict__ ab)
{
    __shared__ float bs[8192];          // 32 KB: two 16 KB halves
    const int tid  = threadIdx.x;
    const int bi   = blockIdx.x;        // 512 = 8 b * 64 q-tiles
    const int b    = bi >> 6;
    const int q0   = (bi & 63) * 16;
    const int lane = tid & 63;
    const int w    = tid >> 6;          // wave = head
    const int ln   = lane & 15;
    const int g    = lane >> 4;

    const short8 qf = *(const short8*)(qbuf + ((size_t)(b*8+w)*1024 + q0 + ln)*32 + g*8);

    // staging decode (r3 verbatim): thread stages granule `lane` of rows 2w, 2w+1
    const int h2s  = lane & 1;
    const int keys = lane >> 1;
    const int ts   = keys >> 4;
    const int rs   = keys & 3;
    const int gs   = (keys >> 2) & 3;
    const int base0 = (128*ts + 32*rs + 16*h2s + gs) * 16;
    const int xrs   = (8*ts + 2*rs + h2s) & 15;
    const int qxa   = (2*w)     ^ xrs;
    const int qxb   = (2*w + 1) ^ xrs;

    const float* bp0 = bias + ((size_t)(b*1024 + q0 + 2*w)*1024)*8 + lane*4;
    const unsigned short* kp = kbuf  + ((size_t)(b*8+w)*1024 + ln)*32 + g*8;
    const unsigned short* vp = vtbuf + ((size_t)(b*8+w)*32   + ln)*1024 + g*8;
    const unsigned int*  bmp = bm + (size_t)(b*1024 + q0 + ln)*32;

    f32x4 acc0 = (f32x4){0.f,0.f,0.f,0.f};
    f32x4 acc1 = (f32x4){0.f,0.f,0.f,0.f};
    float lsum = 0.f;
    const f32x4 z4 = {0.f,0.f,0.f,0.f};

    // prefetch regs: bias 4x float4 (2 rows x 2 halves), K 4x short8, bm 2
    float4 b00, b01, b10, b11;
    short8 kn0, kn1, kn2, kn3;
    unsigned int bm0, bm1;

#define LOAD_ALL(cc) do { int c_ = (cc); \
    b00 = *(const float4*)(bp0 + (size_t)c_*512); \
    b01 = *(const float4*)(bp0 + (size_t)c_*512 + 256); \
    b10 = *(const float4*)(bp0 + (size_t)c_*512 + 8192); \
    b11 = *(const float4*)(bp0 + (size_t)c_*512 + 8192 + 256); \
    kn0 = *(const short8*)(kp + c_*2048); \
    kn1 = *(const short8*)(kp + c_*2048 + 512); \
    kn2 = *(const short8*)(kp + c_*2048 + 1024); \
    kn3 = *(const short8*)(kp + c_*2048 + 1536); \
    bm0 = bmp[2*c_]; bm1 = bmp[2*c_+1]; } while(0)

// one 32-key half: S^T MFMAs, bias+mask+exp, pack, lazy-V PV (r3 formulas)
#define CHUNK_HALF(K0, K1, BMW, BOFF, VOFF) do { \
    f32x4 s0 = MFMA16(K0, qf, z4); \
    f32x4 s1 = MFMA16(K1, qf, z4); \
    short8 vf0 = *(const short8*)(vp + (VOFF)); \
    short8 vf1 = *(const short8*)(vp + (VOFF) + 16*1024); \
    float pv[8]; \
    _Pragma("unroll") for (int t=0; t<2; ++t){ \
        _Pragma("unroll") for (int r=0; r<4; ++r){ \
            int keyl = t*16 + g*4 + r; \
            int bidx = (BOFF) + (t*128 + r*32 + w*4 + g)*16 + (ln ^ ((t*8 + r*2 + (w>>2)) & 15)); \
            float sv = (t ? s1[r] : s0[r]) + bs[bidx]; \
            sv = (((BMW) >> keyl) & 1u) ? -1e30f : sv; \
            float p = __expf(sv); \
            pv[t*4+r] = p; \
            lsum += p; \
        } \
    } \
    unsigned int A01 = f2bf(pv[0]) | (f2bf(pv[1])<<16); \
    unsigned int A23 = f2bf(pv[2]) | (f2bf(pv[3])<<16); \
    unsigned int B01 = f2bf(pv[4]) | (f2bf(pv[5])<<16); \
    unsigned int B23 = f2bf(pv[6]) | (f2bf(pv[7])<<16); \
    int s0l = (2*(g&1))*16 + ln; \
    int s1l = s0l + 16; \
    unsigned int a01  = (unsigned int)__shfl((int)A01, s0l); \
    unsigned int a23  = (unsigned int)__shfl((int)A23, s0l); \
    unsigned int c01  = (unsigned int)__shfl((int)B01, s0l); \
    unsigned int c23  = (unsigned int)__shfl((int)B23, s0l); \
    unsigned int a01b = (unsigned int)__shfl((int)A01, s1l); \
    unsigned int a23b = (unsigned int)__shfl((int)A23, s1l); \
    unsigned int c01b = (unsigned int)__shfl((int)B01, s1l); \
    unsigned int c23b = (unsigned int)__shfl((int)B23, s1l); \
    bool hi_ = (g >= 2); \
    int4 pw_ = make_int4((int)(hi_ ? c01  : a01 ), (int)(hi_ ? c23  : a23 ), \
                         (int)(hi_ ? c01b : a01b), (int)(hi_ ? c23b : a23b)); \
    short8 pf_ = *(short8*)&pw_; \
    acc0 = MFMA16(vf0, pf_, acc0); \
    acc1 = MFMA16(vf1, pf_, acc1); } while(0)

    // prologue: chunk 0
    LOAD_ALL(0);
    bm0 &= ~1u;                         // col 0 force-unmasked (chunk 0, word 0)

    #pragma unroll 1
    for (int cc = 0; cc < 16; ++cc){
        // stage both 32-key halves from regs loaded last phase
        bs[base0       + qxa] = b00.x;  bs[base0 +  64 + qxa] = b00.y;
        bs[base0 + 128 + qxa] = b00.z;  bs[base0 + 192 + qxa] = b00.w;
        bs[base0       + qxb] = b10.x;  bs[base0 +  64 + qxb] = b10.y;
        bs[base0 + 128 + qxb] = b10.z;  bs[base0 + 192 + qxb] = b10.w;
        bs[4096 + base0       + qxa] = b01.x;  bs[4096 + base0 +  64 + qxa] = b01.y;
        bs[4096 + base0 + 128 + qxa] = b01.z;  bs[4096 + base0 + 192 + qxa] = b01.w;
        bs[4096 + base0       + qxb] = b11.x;  bs[4096 + base0 +  64 + qxb] = b11.y;
        bs[4096 + base0 + 128 + qxb] = b11.z;  bs[4096 + base0 + 192 + qxb] = b11.w;

        // snapshot K/mask of current chunk BEFORE reload (r6 lesson)
        short8 ck0 = kn0, ck1 = kn1, ck2 = kn2, ck3 = kn3;
        unsigned int cb0 = bm0, cb1 = bm1;
        if (cc + 1 < 16) LOAD_ALL(cc + 1);
        __syncthreads();

        CHUNK_HALF(ck0, ck1, cb0, 0,    cc*64);
        CHUNK_HALF(ck2, ck3, cb1, 4096, cc*64 + 32);
        __syncthreads();
    }

    float ps = lsum;
    ps += __shfl_xor(ps, 16);
    ps += __shfl_xor(ps, 32);
    float inv = 1.0f / ps;
    {
        int n = q0 + ln;
        unsigned int lo0 = f2bf(acc0[0]*inv) | (f2bf(acc0[1]*inv)<<16);
        unsigned int hi0 = f2bf(acc0[2]*inv) | (f2bf(acc0[3]*inv)<<16);
        *(uint2*)(ab + ((size_t)(b*1024 + n))*256 + w*32 + g*4) = make_uint2(lo0,hi0);
        unsigned int lo1 = f2bf(acc1[0]*inv) | (f2bf(acc1[1]*inv)<<16);
        unsigned int hi1 = f2bf(acc1[2]*inv) | (f2bf(acc1[3]*inv)<<16);
        *(uint2*)(ab + ((size_t)(b*1024 + n))*256 + w*32 + 16 + g*4) = make_uint2(lo1,hi1);
    }
#undef LOAD_ALL
#undef CHUNK_HALF
}

// ---------------- Output projection (32-row tiles) ----------------
__global__ __launch_bounds__(256) void oproj_k(
    const unsigned short* __restrict__ ab, const float* __restrict__ Wop,
    const float* __restrict__ bop, float* __restrict__ out)
{
    __shared__ __align__(16) unsigned short al[32*264];
    const int tid = threadIdx.x;
    const int R0 = blockIdx.x * 32;   // 256 blocks
    #pragma unroll
    for (int it=0; it<4; ++it){
        int f8 = it*256 + tid;
        int r = f8 >> 5, c8 = f8 & 31;
        *(short8*)&al[r*264 + c8*8] = *(const short8*)(ab + (size_t)(R0+r)*256 + c8*8);
    }
    __syncthreads();
    const int lane = tid & 63;
    const int w = tid >> 6, ln = lane & 15, g = lane >> 4;
    const int ow = w*64;
    f32x4 acc[4][2];
    #pragma unroll
    for (int a=0;a<4;++a){ acc[a][0]=(f32x4){0.f,0.f,0.f,0.f}; acc[a][1]=(f32x4){0.f,0.f,0.f,0.f}; }
    for (int kk=0;kk<8;++kk){
        short8 wf[4], xf[2];
        #pragma unroll
        for (int ot=0;ot<4;++ot){
            const float* wp = Wop + (size_t)(ow+ot*16+ln)*256 + kk*32 + g*8;
            wf[ot] = pack8(*(const float4*)wp, *(const float4*)(wp+4));
        }
        #pragma unroll
        for (int nt=0;nt<2;++nt)
            xf[nt] = *(const short8*)&al[(nt*16+ln)*264 + kk*32 + g*8];
        #pragma unroll
        for (int ot=0;ot<4;++ot){
            #pragma unroll
            for (int nt=0;nt<2;++nt)
                acc[ot][nt] = MFMA16(wf[ot], xf[nt], acc[ot][nt]);
        }
    }
    #pragma unroll
    for (int ot=0;ot<4;++ot){
        int o0 = ow + ot*16 + g*4;
        float4 b4 = *(const float4*)(bop + o0);
        #pragma unroll
        for (int nt=0;nt<2;++nt){
            int n = R0 + nt*16 + ln;
            float4 res;
            res.x = acc[ot][nt][0] + b4.x;
            res.y = acc[ot][nt][1] + b4.y;
            res.z = acc[ot][nt][2] + b4.z;
            res.w = acc[ot][nt][3] + b4.w;
            *(float4*)(out + (size_t)n*256 + o0) = res;
        }
    }
}

extern "C" void kernel_launch(void* const* d_in, const int* in_sizes, int n_in,
                              void* d_out, int out_size, void* d_ws, size_t ws_size,
                              hipStream_t stream)
{
    (void)in_sizes; (void)n_in; (void)out_size; (void)ws_size;
    const float* nd   = (const float*)d_in[0];
    // d_in[1] = N scalar (compile-time 1024 here)
    const float* bias = (const float*)d_in[2];
    const int* mask   = (const int*)d_in[3];
    const float* Wq = (const float*)d_in[4];
    const float* bq = (const float*)d_in[5];
    const float* Wk = (const float*)d_in[6];
    const float* bk = (const float*)d_in[7];
    const float* Wv = (const float*)d_in[8];
    const float* bv = (const float*)d_in[9];
    const float* Wo = (const float*)d_in[10];
    const float* bo = (const float*)d_in[11];
    float* out = (float*)d_out;

    const size_t ELEMS = (size_t)8*8*1024*32;   // 2M bf16 per buffer
    unsigned short* qb  = (unsigned short*)d_ws;
    unsigned short* kb  = qb  + ELEMS;
    unsigned short* vtb = kb  + ELEMS;
    unsigned short* ab  = vtb + ELEMS;
    unsigned int* bmw   = (unsigned int*)(ab + ELEMS);  // 1MB bitmask

    mask_prep_k<<<1024, 256, 0, stream>>>((const unsigned int*)mask, bmw);
    qkv_proj_k<<<384, 256, 0, stream>>>(nd, Wq, bq, Wk, bk, Wv, bv, qb, kb, vtb);
    attn_k<<<512, 512, 0, stream>>>(qb, kb, vtb, bias, bmw, ab);
    oproj_k<<<256, 256, 0, stream>>>(ab, Wo, bo, out);
}